// Round 1
// baseline (999.424 us; speedup 1.0000x reference)
//
#include <hip/hip_runtime.h>

#define D_MODEL 1024
#define N_HEADS 16
#define DH 64
#define N_LAYERS 4
#define N_LEVELS 8
#define BB 2
#define TT 1024
#define MM (BB*TT)
#define EPSV 1e-5f

typedef float f32x4 __attribute__((ext_vector_type(4)));
typedef short bf16x8 __attribute__((ext_vector_type(8)));

__device__ __forceinline__ float bf2f(unsigned short u) {
    union { unsigned int i; float f; } c; c.i = ((unsigned int)u) << 16; return c.f;
}
__device__ __forceinline__ unsigned short f2bf(float f) {
    union { float f; unsigned int i; } c; c.f = f;
    unsigned int x = c.i;
    return (unsigned short)((x + 0x7fffu + ((x >> 16) & 1u)) >> 16);  // RNE
}
__device__ __forceinline__ float cvt_in(const void* src, long long j, int isbf) {
    return isbf ? bf2f(((const unsigned short*)src)[j]) : ((const float*)src)[j];
}

// async global->LDS, 16 B per lane; LDS dest = wave-uniform base + lane*16
__device__ __forceinline__ void gl_lds16(const unsigned short* g, unsigned short* l) {
    __builtin_amdgcn_global_load_lds(
        (const __attribute__((address_space(1))) unsigned int*)g,
        (__attribute__((address_space(3))) unsigned int*)l,
        16, 0, 0);
}

// ---- dtype detection (fp32 vs bf16 input buffers) ----
__global__ void detect_kernel(const unsigned short* __restrict__ x, int* __restrict__ flag) {
    __shared__ int cnts[256];
    int cnt = 0;
    for (int i = threadIdx.x; i < 16384; i += 256) {
        unsigned short u = x[2 * i];
        int e = (u >> 7) & 0xFF;
        if (e >= 110 && e <= 140) cnt++;
    }
    cnts[threadIdx.x] = cnt;
    __syncthreads();
    for (int s = 128; s; s >>= 1) {
        if (threadIdx.x < s) cnts[threadIdx.x] += cnts[threadIdx.x + s];
        __syncthreads();
    }
    if (threadIdx.x == 0) flag[0] = (cnts[0] > 12000) ? 1 : 0;
}

// ---- converters ----
__global__ void load_f32_kernel(const void* __restrict__ src, float* __restrict__ dst,
                                const int* __restrict__ flag, int n) {
    int i = blockIdx.x * 256 + threadIdx.x;
    if (i >= n) return;
    dst[i] = cvt_in(src, i, flag[0]);
}
__global__ void load_small_kernel(const void* m_in, const void* aa, const void* af_,
                                  const void* bo, const void* b1, const void* b2,
                                  float* mf, float* embA, float* embF,
                                  float* boutf, float* b1f, float* b2f,
                                  const int* __restrict__ flag) {
    int i = blockIdx.x * 256 + threadIdx.x;
    int isbf = flag[0];
    if (i < 2048)        mf[i] = cvt_in(m_in, i, isbf);
    else if (i < 67584)  embA[i - 2048] = cvt_in(aa, i - 2048, isbf);
    else if (i < 133120) embF[i - 67584] = cvt_in(af_, i - 67584, isbf);
    else if (i < 137216) boutf[i - 133120] = cvt_in(bo, i - 133120, isbf);
    else if (i < 153600) b1f[i - 137216] = cvt_in(b1, i - 137216, isbf);
    else if (i < 157696) b2f[i - 153600] = cvt_in(b2, i - 153600, isbf);
}

// ---- per-layer fused weight transpose: dst(N,K) bf16 <- src(K,N) ----
__global__ __launch_bounds__(256)
void transpose_layer_kernel(const void* Wqkv, const void* Wo, const void* W1, const void* W2,
                            unsigned short* wq, unsigned short* wo,
                            unsigned short* w1, unsigned short* w2,
                            const int* __restrict__ flag,
                            long long o_qkv, long long o_o, long long o_1, long long o_2) {
    __shared__ float tile[32][33];
    int bid = blockIdx.x;
    const void* src; unsigned short* dst; long long off; int N, K, nt, kt;
    if (bid < 3072)      { int t = bid;        src = Wqkv; dst = wq; off = o_qkv; N = 3072; K = 1024; nt = t % 96;  kt = t / 96; }
    else if (bid < 4096) { int t = bid - 3072; src = Wo;   dst = wo; off = o_o;   N = 1024; K = 1024; nt = t % 32;  kt = t / 32; }
    else if (bid < 8192) { int t = bid - 4096; src = W1;   dst = w1; off = o_1;   N = 4096; K = 1024; nt = t % 128; kt = t / 128; }
    else                 { int t = bid - 8192; src = W2;   dst = w2; off = o_2;   N = 1024; K = 4096; nt = t % 32;  kt = t / 32; }
    int n0 = nt * 32, k0 = kt * 32;
    int r = threadIdx.x >> 5, c = threadIdx.x & 31;
    int isbf = flag[0];
    #pragma unroll
    for (int rr = 0; rr < 4; ++rr) {
        int k = k0 + r + rr * 8;
        tile[r + rr * 8][c] = cvt_in(src, off + (long long)k * N + n0 + c, isbf);
    }
    __syncthreads();
    #pragma unroll
    for (int rr = 0; rr < 4; ++rr) {
        int n = n0 + r + rr * 8;
        dst[(size_t)n * K + k0 + c] = f2bf(tile[c][r + rr * 8]);
    }
}

// ---- dual block reduction (blockDim.x == 256) ----
__device__ __forceinline__ void blk_sum2_256(float& a, float& b, float* red) {
    #pragma unroll
    for (int off = 32; off; off >>= 1) {
        a += __shfl_down(a, off, 64);
        b += __shfl_down(b, off, 64);
    }
    int tid = threadIdx.x;
    __syncthreads();
    if ((tid & 63) == 0) { red[tid >> 6] = a; red[4 + (tid >> 6)] = b; }
    __syncthreads();
    a = red[0] + red[1] + red[2] + red[3];
    b = red[4] + red[5] + red[6] + red[7];
}

// ---- AdaLN (single pass mean/var; masked rows write zeros directly) ----
__global__ __launch_bounds__(256)
void adaln_kernel(const float* __restrict__ x,
                  const float* __restrict__ emb,
                  const int* __restrict__ lvl,
                  const float* __restrict__ mvec,
                  unsigned short* __restrict__ h) {
    __shared__ float red[8];
    int row = blockIdx.x;
    int b = row / TT;
    int tid = threadIdx.x;
    const float* xr = x + (size_t)row * D_MODEL;
    float mval = mvec[row];
    unsigned short* hr = h + (size_t)row * D_MODEL;

    if (mval == 0.0f) {   // block-uniform: whole block is one row
        for (int j = tid; j < D_MODEL; j += 256) hr[j] = 0;
        return;
    }

    float s = 0.f, ss = 0.f;
    for (int j = tid; j < D_MODEL; j += 256) { float v = xr[j]; s += v; ss += v * v; }
    blk_sum2_256(s, ss, red);
    float mu = s * (1.0f / D_MODEL);
    float var = ss * (1.0f / D_MODEL) - mu * mu;
    float rstd = rsqrtf(var + EPSV);

    int lv = lvl[b];
    const float* g = emb + (size_t)lv * (2 * D_MODEL);
    for (int j = tid; j < D_MODEL; j += 256) {
        float hn = (xr[j] - mu) * rstd;
        float h2 = 2.0f * (1.0f - 0.1f * hn) * hn;
        float o = __expf(g[j]) * h2 + g[D_MODEL + j];
        hr[j] = f2bf(o * mval);
    }
}

// ---- MFMA GEMM (generalized wave count; verified configs unchanged) ----
#define EPI_STORE 0
#define EPI_GELU  1
#define EPI_RESID 2
#define EPI_PART  3

template<int MI, int NI, int WR, int WC>
__global__ __launch_bounds__(WR * WC * 64)
void gemm8_kernel(const unsigned short* __restrict__ A, int lda,
                  const unsigned short* __restrict__ BT, int ldb,
                  const float* __restrict__ bias,
                  unsigned short* __restrict__ outb,
                  const float* __restrict__ xin,
                  float* __restrict__ xout,
                  const float* __restrict__ mvec,
                  float* __restrict__ pbuf,
                  int M, int N, int K, int mode) {
    constexpr int BM = WR * MI * 16;
    constexpr int BN = WC * NI * 16;
    constexpr int NW = WR * WC;
    __shared__ __align__(16) unsigned short As[BM * 32];
    __shared__ __align__(16) unsigned short Bs[BN * 32];
    __shared__ int alive;
    int tid = threadIdx.x;
    int wave = tid >> 6;
    int lane = tid & 63;
    int quad = lane >> 4;
    int l16  = lane & 15;
    int tileM = blockIdx.y * BM;
    int tileN = blockIdx.x * BN;
    int wm = (wave % WR) * MI * 16;
    int wn = (wave / WR) * NI * 16;

    // mask-skip: if every row of this M-tile is masked, skip the K-loop;
    // epilogue then writes exact zeros (STORE/PART) or (xin+bias)*0 (RESID).
    if (tid == 0) alive = 0;
    __syncthreads();
    if (tid < BM && mvec[tileM + tid] != 0.0f) alive = 1;
    __syncthreads();

    f32x4 acc[MI][NI] = {};

    if (alive) {
        long long zoff = (long long)blockIdx.z * K;
        const unsigned short* Ab = A  + zoff + (size_t)(tileM + (lane >> 2)) * lda + (lane & 3) * 8;
        const unsigned short* Bb = BT + zoff + (size_t)(tileN + (lane >> 2)) * ldb + (lane & 3) * 8;

        for (int k0 = 0; k0 < K; k0 += 32) {
            for (int st = wave; st < BM / 16; st += NW)
                gl_lds16(Ab + (size_t)st * 16 * lda + k0, &As[st * 512]);
            for (int st = wave; st < BN / 16; st += NW)
                gl_lds16(Bb + (size_t)st * 16 * ldb + k0, &Bs[st * 512]);
            __syncthreads();

            bf16x8 af[MI], bf[NI];
            #pragma unroll
            for (int mi = 0; mi < MI; ++mi)
                af[mi] = *(const bf16x8*)(&As[(wm + mi * 16 + l16) * 32 + quad * 8]);
            #pragma unroll
            for (int ni = 0; ni < NI; ++ni)
                bf[ni] = *(const bf16x8*)(&Bs[(wn + ni * 16 + l16) * 32 + quad * 8]);
            #pragma unroll
            for (int mi = 0; mi < MI; ++mi)
                #pragma unroll
                for (int ni = 0; ni < NI; ++ni)
                    acc[mi][ni] = __builtin_amdgcn_mfma_f32_16x16x32_bf16(af[mi], bf[ni], acc[mi][ni], 0, 0, 0);
            __syncthreads();
        }
    }

    #pragma unroll
    for (int mi = 0; mi < MI; ++mi)
    #pragma unroll
    for (int ni = 0; ni < NI; ++ni) {
        #pragma unroll
        for (int r = 0; r < 4; ++r) {
            int row = tileM + wm + mi * 16 + quad * 4 + r;
            int col = tileN + wn + ni * 16 + l16;
            float v = acc[mi][ni][r];
            size_t idx = (size_t)row * N + col;
            if (mode == EPI_STORE) {
                outb[idx] = f2bf(v);
            } else if (mode == EPI_GELU) {
                v += bias[col];
                float gel = 0.5f * v * (1.0f + erff(v * 0.70710678118654752f));
                outb[idx] = f2bf(gel);
            } else if (mode == EPI_RESID) {
                v += bias[col];
                xout[idx] = (xin[idx] + v) * mvec[row];
            } else {
                pbuf[(size_t)blockIdx.z * M * N + idx] = v;
            }
        }
    }
}

// ---- split-j flash attention: 2 blocks per (qt,hd,b), j-tiles by parity ----
#define FA_DPAD 72

__global__ __launch_bounds__(256)
void fattn_split_kernel(const unsigned short* __restrict__ qkv,
                        const float* __restrict__ mvec,
                        float* __restrict__ Opart,   // [2][MM][1024] fp32 unnormalized
                        float* __restrict__ ml) {    // [2][MM][16][2] fp32 (m,l)
    __shared__ __align__(16) unsigned short Qs[64 * FA_DPAD];
    __shared__ __align__(16) unsigned short Ks[64 * FA_DPAD];
    __shared__ __align__(16) unsigned short Vs[64 * FA_DPAD];
    __shared__ __align__(16) unsigned short Ps[64 * FA_DPAD];
    __shared__ int alive_s;

    int qt  = blockIdx.x;            // 0..15
    int hd  = blockIdx.y;
    int b   = blockIdx.z >> 1;
    int s   = blockIdx.z & 1;        // j-parity split
    int tid = threadIdx.x;
    int wave = tid >> 6;
    int lane = tid & 63;
    int quad = lane >> 4;
    int l16  = lane & 15;

    // mask-skip: whole q-tile masked -> write zero partials with (m=0, l=1)
    if (tid == 0) alive_s = 0;
    __syncthreads();
    if (tid < 64 && mvec[(size_t)b * TT + qt * 64 + tid] != 0.0f) alive_s = 1;
    __syncthreads();
    bool alive = alive_s != 0;

    const unsigned short* base = qkv + (size_t)b * TT * 3072;

    f32x4 Oacc[4] = {};
    float mstate[4], lstate[4];
    #pragma unroll
    for (int r = 0; r < 4; ++r) {
        mstate[r] = alive ? -1e30f : 0.f;
        lstate[r] = alive ? 0.f : 1.f;
    }

    if (alive) {
        {
            int r = tid >> 2, c = (tid & 3) * 16;
            const unsigned short* src = base + (size_t)(qt * 64 + r) * 3072 + hd * DH + c;
            *(uint4*)(&Qs[r * FA_DPAD + c])     = *(const uint4*)(src);
            *(uint4*)(&Qs[r * FA_DPAD + c + 8]) = *(const uint4*)(src + 8);
        }
        __syncthreads();

        bf16x8 aq[2];
        #pragma unroll
        for (int cc = 0; cc < 2; ++cc)
            aq[cc] = *(const bf16x8*)(&Qs[(wave * 16 + l16) * FA_DPAD + cc * 32 + quad * 8]);

        for (int jt = s; jt <= qt; jt += 2) {
            __syncthreads();
            {
                int r = tid >> 2, c = (tid & 3) * 16;
                const unsigned short* src = base + (size_t)(jt * 64 + r) * 3072 + 1024 + hd * DH + c;
                *(uint4*)(&Ks[r * FA_DPAD + c])     = *(const uint4*)(src);
                *(uint4*)(&Ks[r * FA_DPAD + c + 8]) = *(const uint4*)(src + 8);
            }
            {
                int j = lane, c = wave * 16;
                const unsigned short* src = base + (size_t)(jt * 64 + j) * 3072 + 2048 + hd * DH + c;
                unsigned short tmp[16];
                *(uint4*)(tmp)     = *(const uint4*)(src);
                *(uint4*)(tmp + 8) = *(const uint4*)(src + 8);
                #pragma unroll
                for (int d = 0; d < 16; ++d) Vs[(c + d) * FA_DPAD + j] = tmp[d];
            }
            __syncthreads();

            f32x4 S[4] = {};
            #pragma unroll
            for (int t = 0; t < 4; ++t)
                #pragma unroll
                for (int cc = 0; cc < 2; ++cc) {
                    bf16x8 bk = *(const bf16x8*)(&Ks[(t * 16 + l16) * FA_DPAD + cc * 32 + quad * 8]);
                    S[t] = __builtin_amdgcn_mfma_f32_16x16x32_bf16(aq[cc], bk, S[t], 0, 0, 0);
                }

            int qrow0 = qt * 64 + wave * 16 + quad * 4;
            bool diag = (jt == qt);
            float mnew[4];
            #pragma unroll
            for (int r = 0; r < 4; ++r) {
                float v = -1e30f;
                #pragma unroll
                for (int t = 0; t < 4; ++t) {
                    float sv = S[t][r] * 0.125f;
                    if (diag) {
                        int j = jt * 64 + t * 16 + l16;
                        if (j > qrow0 + r) sv = -1e30f;
                    }
                    S[t][r] = sv;
                    v = fmaxf(v, sv);
                }
                v = fmaxf(v, __shfl_xor(v, 1, 64));
                v = fmaxf(v, __shfl_xor(v, 2, 64));
                v = fmaxf(v, __shfl_xor(v, 4, 64));
                v = fmaxf(v, __shfl_xor(v, 8, 64));
                mnew[r] = fmaxf(mstate[r], v);
            }

            #pragma unroll
            for (int r = 0; r < 4; ++r) {
                float rs = 0.f;
                #pragma unroll
                for (int t = 0; t < 4; ++t) {
                    float p = __expf(S[t][r] - mnew[r]);
                    rs += p;
                    Ps[(wave * 16 + quad * 4 + r) * FA_DPAD + t * 16 + l16] = f2bf(p);
                }
                rs += __shfl_xor(rs, 1, 64);
                rs += __shfl_xor(rs, 2, 64);
                rs += __shfl_xor(rs, 4, 64);
                rs += __shfl_xor(rs, 8, 64);
                float alpha = __expf(mstate[r] - mnew[r]);
                lstate[r] = alpha * lstate[r] + rs;
                mstate[r] = mnew[r];
                #pragma unroll
                for (int t = 0; t < 4; ++t) Oacc[t][r] *= alpha;
            }

            #pragma unroll
            for (int cc = 0; cc < 2; ++cc) {
                bf16x8 ap = *(const bf16x8*)(&Ps[(wave * 16 + l16) * FA_DPAD + cc * 32 + quad * 8]);
                #pragma unroll
                for (int t = 0; t < 4; ++t) {
                    bf16x8 bv = *(const bf16x8*)(&Vs[(t * 16 + l16) * FA_DPAD + cc * 32 + quad * 8]);
                    Oacc[t] = __builtin_amdgcn_mfma_f32_16x16x32_bf16(ap, bv, Oacc[t], 0, 0, 0);
                }
            }
        }
    }

    // store unnormalized partials + (m,l)
    #pragma unroll
    for (int r = 0; r < 4; ++r) {
        int qi = qt * 64 + wave * 16 + quad * 4 + r;
        size_t row = (size_t)b * TT + qi;
        float* orow = Opart + (size_t)s * MM * D_MODEL + row * D_MODEL + hd * DH;
        #pragma unroll
        for (int t = 0; t < 4; ++t)
            orow[t * 16 + l16] = Oacc[t][r];
        if (l16 == 0) {
            float* mlp = ml + (((size_t)s * MM + row) * N_HEADS + hd) * 2;
            mlp[0] = mstate[r];
            mlp[1] = lstate[r];
        }
    }
}

// merge two j-splits -> normalized bf16 ob
__global__ void attn_merge_kernel(const float* __restrict__ Opart,
                                  const float* __restrict__ ml,
                                  unsigned short* __restrict__ ob) {
    int i = blockIdx.x * 256 + threadIdx.x;   // over MM*1024
    int row = i >> 10;
    int hd  = (i >> 6) & 15;
    const float* ml0 = ml + (((size_t)row) * N_HEADS + hd) * 2;
    const float* ml1 = ml + (((size_t)MM + row) * N_HEADS + hd) * 2;
    float m0 = ml0[0], l0 = ml0[1];
    float m1 = ml1[0], l1 = ml1[1];
    float M = fmaxf(m0, m1);
    float w0 = __expf(m0 - M), w1 = __expf(m1 - M);
    float den = w0 * l0 + w1 * l1;
    float num = w0 * Opart[i] + w1 * Opart[(size_t)MM * D_MODEL + i];
    ob[i] = f2bf(num / den);
}

// combine 2 split-K partials + bias + residual + mask; optional fused final store
__global__ void combine2_kernel(float* __restrict__ xf,
                                const float* __restrict__ pbuf,
                                const float* __restrict__ bias,
                                const float* __restrict__ mvec,
                                void* __restrict__ outp,
                                const int* __restrict__ flag, int n) {
    int i = blockIdx.x * 256 + threadIdx.x;
    if (i >= n) return;
    int row = i >> 10, col = i & 1023;
    float v = (xf[i] + pbuf[i] + pbuf[n + i] + bias[col]) * mvec[row];
    xf[i] = v;
    if (outp) {
        if (flag[0]) ((unsigned short*)outp)[i] = f2bf(v);
        else         ((float*)outp)[i] = v;
    }
}

// ---- workspace layout (bytes) ----
#define MB (1048576u)
#define WS_FLAG   0u
#define WS_MF     4096u
#define WS_EMBA   (WS_MF + 8192u)
#define WS_EMBF   (WS_EMBA + 262144u)
#define WS_BOUT   (WS_EMBF + 262144u)
#define WS_B1     (WS_BOUT + 16384u)
#define WS_B2     (WS_B1 + 65536u)
#define WS_XF     (1u*MB)    // 8 MB fp32 x
#define WS_H      (9u*MB)    // 4 MB bf16 h | ml (512 KB) after qkv GEMM | W2 partials (FFN)
#define WS_QKV    (13u*MB)   // 12 MB bf16
#define WS_OB     (25u*MB)   // 4 MB bf16
#define WS_PART   (9u*MB)    // 16 MB fp32 W2 split-K partials (FFN phase, h/qkv dead)
#define WS_ML     (9u*MB)    // 512 KB fp32 attn (m,l)   (attention phase, h dead)
#define WS_FF1    (29u*MB)   // 16 MB bf16 ff1 (FFN) | attn O-partials (attention phase)
#define WS_OPART  (29u*MB)
#define WS_WQKV   (45u*MB)   // 6 MB (3072 x 1024)
#define WS_WOUT   (51u*MB)   // 2 MB
#define WS_W1     (53u*MB)   // 8 MB (4096 x 1024)
#define WS_W2     (61u*MB)   // 8 MB (1024 x 4096)  end: 69 MB

extern "C" void kernel_launch(void* const* d_in, const int* in_sizes, int n_in,
                              void* d_out, int out_size, void* d_ws, size_t ws_size,
                              hipStream_t stream) {
    const void* x_in  = d_in[0];
    const void* m_in  = d_in[1];
    const int*  l_in  = (const int*)d_in[2];
    const void* Wqkv  = d_in[3];
    const void* Wout  = d_in[4];
    const void* boutp = d_in[5];
    const void* ada_a = d_in[6];
    const void* ada_f = d_in[7];
    const void* W1    = d_in[8];
    const void* b1    = d_in[9];
    const void* W2    = d_in[10];
    const void* b2    = d_in[11];

    char* ws = (char*)d_ws;
    int*            flag = (int*)(ws + WS_FLAG);
    float*          mf   = (float*)(ws + WS_MF);
    float*          embA = (float*)(ws + WS_EMBA);
    float*          embF = (float*)(ws + WS_EMBF);
    float*          boutf= (float*)(ws + WS_BOUT);
    float*          b1f  = (float*)(ws + WS_B1);
    float*          b2f  = (float*)(ws + WS_B2);
    float*          xf   = (float*)(ws + WS_XF);
    unsigned short* h    = (unsigned short*)(ws + WS_H);
    unsigned short* qkv  = (unsigned short*)(ws + WS_QKV);
    unsigned short* ob   = (unsigned short*)(ws + WS_OB);
    float*          part = (float*)(ws + WS_PART);
    float*          mlb  = (float*)(ws + WS_ML);
    float*          opart= (float*)(ws + WS_OPART);
    unsigned short* ff1  = (unsigned short*)(ws + WS_FF1);
    unsigned short* wqkvt= (unsigned short*)(ws + WS_WQKV);
    unsigned short* woutt= (unsigned short*)(ws + WS_WOUT);
    unsigned short* w1t  = (unsigned short*)(ws + WS_W1);
    unsigned short* w2t  = (unsigned short*)(ws + WS_W2);

    const int n = MM * D_MODEL;

    detect_kernel<<<1, 256, 0, stream>>>((const unsigned short*)x_in, flag);
    load_f32_kernel<<<n / 256, 256, 0, stream>>>(x_in, xf, flag, n);
    load_small_kernel<<<(157696 + 255) / 256, 256, 0, stream>>>(
        m_in, ada_a, ada_f, boutp, b1, b2, mf, embA, embF, boutf, b1f, b2f, flag);

    const long long nqkv = (long long)D_MODEL * 3 * D_MODEL;
    const long long nsq  = (long long)D_MODEL * D_MODEL;
    const long long nw1  = (long long)D_MODEL * 4 * D_MODEL;

    for (int i = 0; i < N_LAYERS; ++i) {
        transpose_layer_kernel<<<12288, 256, 0, stream>>>(
            Wqkv, Wout, W1, W2, wqkvt, woutt, w1t, w2t, flag,
            i * nqkv, i * nsq, i * nw1, i * nw1);

        // ---- attention sub-block ----
        adaln_kernel<<<MM, 256, 0, stream>>>(xf, embA + (size_t)i * N_LEVELS * 2 * D_MODEL, l_in, mf, h);
        // qkv: 4-wave 128x64 tiles -> 768 blocks (~2.6 active blocks/CU after skip)
        gemm8_kernel<4,2,2,2><<<dim3(3072 / 64, MM / 128), 256, 0, stream>>>(
            h, 1024, wqkvt, 1024, nullptr, qkv, nullptr, nullptr, mf, nullptr,
            MM, 3072, 1024, EPI_STORE);
        fattn_split_kernel<<<dim3(TT / 64, N_HEADS, BB * 2), 256, 0, stream>>>(qkv, mf, opart, mlb);
        attn_merge_kernel<<<n / 256, 256, 0, stream>>>(opart, mlb, ob);
        gemm8_kernel<2,2,4,2><<<dim3(1024 / 64, MM / 128), 512, 0, stream>>>(
            ob, 1024, woutt, 1024, boutf + (size_t)i * D_MODEL, nullptr, xf, xf, mf, nullptr,
            MM, 1024, 1024, EPI_RESID);
        // ---- FFN sub-block ----
        adaln_kernel<<<MM, 256, 0, stream>>>(xf, embF + (size_t)i * N_LEVELS * 2 * D_MODEL, l_in, mf, h);
        gemm8_kernel<4,2,2,4><<<dim3(4096 / 128, MM / 128), 512, 0, stream>>>(
            h, 1024, w1t, 1024, b1f + (size_t)i * 4 * D_MODEL, ff1, nullptr, nullptr, mf, nullptr,
            MM, 4096, 1024, EPI_GELU);
        gemm8_kernel<2,2,4,2><<<dim3(1024 / 64, MM / 128, 2), 512, 0, stream>>>(
            ff1, 4096, w2t, 4096, nullptr, nullptr, nullptr, nullptr, mf, part,
            MM, 1024, 2048, EPI_PART);
        combine2_kernel<<<n / 256, 256, 0, stream>>>(
            xf, part, b2f + (size_t)i * D_MODEL, mf,
            (i == N_LAYERS - 1) ? d_out : nullptr, flag, n);
    }
}

// Round 2
// 972.109 us; speedup vs baseline: 1.0281x; 1.0281x over previous
//
#include <hip/hip_runtime.h>

#define D_MODEL 1024
#define N_HEADS 16
#define DH 64
#define N_LAYERS 4
#define N_LEVELS 8
#define BB 2
#define TT 1024
#define MM (BB*TT)
#define EPSV 1e-5f

typedef float f32x4 __attribute__((ext_vector_type(4)));
typedef short bf16x8 __attribute__((ext_vector_type(8)));
typedef unsigned short u16x4 __attribute__((ext_vector_type(4)));

__device__ __forceinline__ float bf2f(unsigned short u) {
    union { unsigned int i; float f; } c; c.i = ((unsigned int)u) << 16; return c.f;
}
__device__ __forceinline__ unsigned short f2bf(float f) {
    union { float f; unsigned int i; } c; c.f = f;
    unsigned int x = c.i;
    return (unsigned short)((x + 0x7fffu + ((x >> 16) & 1u)) >> 16);  // RNE
}
__device__ __forceinline__ float cvt_in(const void* src, long long j, int isbf) {
    return isbf ? bf2f(((const unsigned short*)src)[j]) : ((const float*)src)[j];
}

// async global->LDS, 16 B per lane; LDS dest = wave-uniform base + lane*16
__device__ __forceinline__ void gl_lds16(const unsigned short* g, unsigned short* l) {
    __builtin_amdgcn_global_load_lds(
        (const __attribute__((address_space(1))) unsigned int*)g,
        (__attribute__((address_space(3))) unsigned int*)l,
        16, 0, 0);
}

// ---- dtype detection (fp32 vs bf16 input buffers) ----
__global__ void detect_kernel(const unsigned short* __restrict__ x, int* __restrict__ flag) {
    __shared__ int cnts[256];
    int cnt = 0;
    for (int i = threadIdx.x; i < 16384; i += 256) {
        unsigned short u = x[2 * i];
        int e = (u >> 7) & 0xFF;
        if (e >= 110 && e <= 140) cnt++;
    }
    cnts[threadIdx.x] = cnt;
    __syncthreads();
    for (int s = 128; s; s >>= 1) {
        if (threadIdx.x < s) cnts[threadIdx.x] += cnts[threadIdx.x + s];
        __syncthreads();
    }
    if (threadIdx.x == 0) flag[0] = (cnts[0] > 12000) ? 1 : 0;
}

// ---- converters ----
__global__ void load_f32_kernel(const void* __restrict__ src, float* __restrict__ dst,
                                const int* __restrict__ flag, int n) {
    int i = blockIdx.x * 256 + threadIdx.x;
    if (i >= n) return;
    dst[i] = cvt_in(src, i, flag[0]);
}
__global__ void load_small_kernel(const void* m_in, const void* aa, const void* af_,
                                  const void* bo, const void* b1, const void* b2,
                                  float* mf, float* embA, float* embF,
                                  float* boutf, float* b1f, float* b2f,
                                  const int* __restrict__ flag) {
    int i = blockIdx.x * 256 + threadIdx.x;
    int isbf = flag[0];
    if (i < 2048)        mf[i] = cvt_in(m_in, i, isbf);
    else if (i < 67584)  embA[i - 2048] = cvt_in(aa, i - 2048, isbf);
    else if (i < 133120) embF[i - 67584] = cvt_in(af_, i - 67584, isbf);
    else if (i < 137216) boutf[i - 133120] = cvt_in(bo, i - 133120, isbf);
    else if (i < 153600) b1f[i - 137216] = cvt_in(b1, i - 137216, isbf);
    else if (i < 157696) b2f[i - 153600] = cvt_in(b2, i - 153600, isbf);
}

// ---- per-layer fused weight transpose: dst(N,K) bf16 <- src(K,N) ----
__global__ __launch_bounds__(256)
void transpose_layer_kernel(const void* Wqkv, const void* Wo, const void* W1, const void* W2,
                            unsigned short* wq, unsigned short* wo,
                            unsigned short* w1, unsigned short* w2,
                            const int* __restrict__ flag,
                            long long o_qkv, long long o_o, long long o_1, long long o_2) {
    __shared__ float tile[32][33];
    int bid = blockIdx.x;
    const void* src; unsigned short* dst; long long off; int N, K, nt, kt;
    if (bid < 3072)      { int t = bid;        src = Wqkv; dst = wq; off = o_qkv; N = 3072; K = 1024; nt = t % 96;  kt = t / 96; }
    else if (bid < 4096) { int t = bid - 3072; src = Wo;   dst = wo; off = o_o;   N = 1024; K = 1024; nt = t % 32;  kt = t / 32; }
    else if (bid < 8192) { int t = bid - 4096; src = W1;   dst = w1; off = o_1;   N = 4096; K = 1024; nt = t % 128; kt = t / 128; }
    else                 { int t = bid - 8192; src = W2;   dst = w2; off = o_2;   N = 1024; K = 4096; nt = t % 32;  kt = t / 32; }
    int n0 = nt * 32, k0 = kt * 32;
    int r = threadIdx.x >> 5, c = threadIdx.x & 31;
    int isbf = flag[0];
    #pragma unroll
    for (int rr = 0; rr < 4; ++rr) {
        int k = k0 + r + rr * 8;
        tile[r + rr * 8][c] = cvt_in(src, off + (long long)k * N + n0 + c, isbf);
    }
    __syncthreads();
    #pragma unroll
    for (int rr = 0; rr < 4; ++rr) {
        int n = n0 + r + rr * 8;
        dst[(size_t)n * K + k0 + c] = f2bf(tile[c][r + rr * 8]);
    }
}

// ---- dual block reduction (blockDim.x == 256) ----
__device__ __forceinline__ void blk_sum2_256(float& a, float& b, float* red) {
    #pragma unroll
    for (int off = 32; off; off >>= 1) {
        a += __shfl_down(a, off, 64);
        b += __shfl_down(b, off, 64);
    }
    int tid = threadIdx.x;
    __syncthreads();
    if ((tid & 63) == 0) { red[tid >> 6] = a; red[4 + (tid >> 6)] = b; }
    __syncthreads();
    a = red[0] + red[1] + red[2] + red[3];
    b = red[4] + red[5] + red[6] + red[7];
}

// ---- AdaLN (single pass mean/var; float4 loads; masked rows write zeros) ----
__global__ __launch_bounds__(256)
void adaln_kernel(const float* __restrict__ x,
                  const float* __restrict__ emb,
                  const int* __restrict__ lvl,
                  const float* __restrict__ mvec,
                  unsigned short* __restrict__ h) {
    __shared__ float red[8];
    int row = blockIdx.x;
    int b = row / TT;
    int tid = threadIdx.x;
    const float* xr = x + (size_t)row * D_MODEL;
    float mval = mvec[row];
    unsigned short* hr = h + (size_t)row * D_MODEL;

    if (mval == 0.0f) {   // block-uniform: whole block is one row
        u16x4 z = (u16x4)0;
        *(u16x4*)(hr + 4 * tid) = z;
        return;
    }

    f32x4 xv = *(const f32x4*)(xr + 4 * tid);
    float s = xv[0] + xv[1] + xv[2] + xv[3];
    float ss = xv[0]*xv[0] + xv[1]*xv[1] + xv[2]*xv[2] + xv[3]*xv[3];
    blk_sum2_256(s, ss, red);
    float mu = s * (1.0f / D_MODEL);
    float var = ss * (1.0f / D_MODEL) - mu * mu;
    float rstd = rsqrtf(var + EPSV);

    int lv = lvl[b];
    const float* g = emb + (size_t)lv * (2 * D_MODEL);
    f32x4 lg = *(const f32x4*)(g + 4 * tid);
    f32x4 lb = *(const f32x4*)(g + D_MODEL + 4 * tid);
    u16x4 r;
    #pragma unroll
    for (int c = 0; c < 4; ++c) {
        float hn = (xv[c] - mu) * rstd;
        float h2 = 2.0f * (1.0f - 0.1f * hn) * hn;
        float o = __expf(lg[c]) * h2 + lb[c];
        r[c] = f2bf(o * mval);
    }
    *(u16x4*)(hr + 4 * tid) = r;
}

// ---- MFMA GEMM: double-buffered LDS, next-tile prefetch (T3 minimum 2-phase) ----
#define EPI_STORE 0
#define EPI_GELU  1
#define EPI_RESID 2
#define EPI_PART  3

template<int MI, int NI, int WR, int WC>
__global__ __launch_bounds__(WR * WC * 64)
void gemm8_kernel(const unsigned short* __restrict__ A, int lda,
                  const unsigned short* __restrict__ BT, int ldb,
                  const float* __restrict__ bias,
                  unsigned short* __restrict__ outb,
                  const float* __restrict__ xin,
                  float* __restrict__ xout,
                  const float* __restrict__ mvec,
                  float* __restrict__ pbuf,
                  int M, int N, int K, int mode) {
    constexpr int BM = WR * MI * 16;
    constexpr int BN = WC * NI * 16;
    constexpr int NW = WR * WC;
    __shared__ __align__(16) unsigned short As[2][BM * 32];
    __shared__ __align__(16) unsigned short Bs[2][BN * 32];
    __shared__ int alive;
    int tid = threadIdx.x;
    int wave = tid >> 6;
    int lane = tid & 63;
    int quad = lane >> 4;
    int l16  = lane & 15;
    int tileM = blockIdx.y * BM;
    int tileN = blockIdx.x * BN;
    int wm = (wave % WR) * MI * 16;
    int wn = (wave / WR) * NI * 16;

    // mask-skip: if every row of this M-tile is masked, skip the K-loop;
    // epilogue then writes exact zeros (STORE/PART) or (xin+bias)*0 (RESID).
    if (tid == 0) alive = 0;
    __syncthreads();
    if (tid < BM && mvec[tileM + tid] != 0.0f) alive = 1;
    __syncthreads();

    f32x4 acc[MI][NI] = {};

    if (alive) {
        long long zoff = (long long)blockIdx.z * K;
        const unsigned short* Ab = A  + zoff + (size_t)(tileM + (lane >> 2)) * lda + (lane & 3) * 8;
        const unsigned short* Bb = BT + zoff + (size_t)(tileN + (lane >> 2)) * ldb + (lane & 3) * 8;

        // prologue: stage K-tile 0 into buffer 0
        for (int st = wave; st < BM / 16; st += NW)
            gl_lds16(Ab + (size_t)st * 16 * lda, &As[0][st * 512]);
        for (int st = wave; st < BN / 16; st += NW)
            gl_lds16(Bb + (size_t)st * 16 * ldb, &Bs[0][st * 512]);
        __syncthreads();

        int cur = 0;
        for (int k0 = 0; k0 < K; k0 += 32) {
            // issue next K-tile's loads first: flight hides under this tile's compute
            if (k0 + 32 < K) {
                for (int st = wave; st < BM / 16; st += NW)
                    gl_lds16(Ab + (size_t)st * 16 * lda + k0 + 32, &As[cur ^ 1][st * 512]);
                for (int st = wave; st < BN / 16; st += NW)
                    gl_lds16(Bb + (size_t)st * 16 * ldb + k0 + 32, &Bs[cur ^ 1][st * 512]);
            }

            bf16x8 af[MI], bf[NI];
            #pragma unroll
            for (int mi = 0; mi < MI; ++mi)
                af[mi] = *(const bf16x8*)(&As[cur][(wm + mi * 16 + l16) * 32 + quad * 8]);
            #pragma unroll
            for (int ni = 0; ni < NI; ++ni)
                bf[ni] = *(const bf16x8*)(&Bs[cur][(wn + ni * 16 + l16) * 32 + quad * 8]);
            #pragma unroll
            for (int mi = 0; mi < MI; ++mi)
                #pragma unroll
                for (int ni = 0; ni < NI; ++ni)
                    acc[mi][ni] = __builtin_amdgcn_mfma_f32_16x16x32_bf16(af[mi], bf[ni], acc[mi][ni], 0, 0, 0);

            // single barrier per K-step: drains vmcnt (next tile landed) + lgkm
            __syncthreads();
            cur ^= 1;
        }
    }

    #pragma unroll
    for (int mi = 0; mi < MI; ++mi)
    #pragma unroll
    for (int ni = 0; ni < NI; ++ni) {
        #pragma unroll
        for (int r = 0; r < 4; ++r) {
            int row = tileM + wm + mi * 16 + quad * 4 + r;
            int col = tileN + wn + ni * 16 + l16;
            float v = acc[mi][ni][r];
            size_t idx = (size_t)row * N + col;
            if (mode == EPI_STORE) {
                outb[idx] = f2bf(v);
            } else if (mode == EPI_GELU) {
                v += bias[col];
                float gel = 0.5f * v * (1.0f + erff(v * 0.70710678118654752f));
                outb[idx] = f2bf(gel);
            } else if (mode == EPI_RESID) {
                v += bias[col];
                xout[idx] = (xin[idx] + v) * mvec[row];
            } else {
                pbuf[(size_t)blockIdx.z * M * N + idx] = v;
            }
        }
    }
}

// ---- split-j flash attention: 2 blocks per (qt,hd,b), j-tiles by parity ----
#define FA_DPAD 72

__global__ __launch_bounds__(256)
void fattn_split_kernel(const unsigned short* __restrict__ qkv,
                        const float* __restrict__ mvec,
                        float* __restrict__ Opart,   // [2][MM][1024] fp32 unnormalized
                        float* __restrict__ ml) {    // [2][MM][16][2] fp32 (m,l)
    __shared__ __align__(16) unsigned short Qs[64 * FA_DPAD];
    __shared__ __align__(16) unsigned short Ks[64 * FA_DPAD];
    __shared__ __align__(16) unsigned short Vs[64 * FA_DPAD];
    __shared__ __align__(16) unsigned short Ps[64 * FA_DPAD];
    __shared__ int alive_s;

    int qt  = blockIdx.x;            // 0..15
    int hd  = blockIdx.y;
    int b   = blockIdx.z >> 1;
    int s   = blockIdx.z & 1;        // j-parity split
    int tid = threadIdx.x;
    int wave = tid >> 6;
    int lane = tid & 63;
    int quad = lane >> 4;
    int l16  = lane & 15;

    // mask-skip: whole q-tile masked -> write zero partials with (m=0, l=1)
    if (tid == 0) alive_s = 0;
    __syncthreads();
    if (tid < 64 && mvec[(size_t)b * TT + qt * 64 + tid] != 0.0f) alive_s = 1;
    __syncthreads();
    bool alive = alive_s != 0;

    const unsigned short* base = qkv + (size_t)b * TT * 3072;

    f32x4 Oacc[4] = {};
    float mstate[4], lstate[4];
    #pragma unroll
    for (int r = 0; r < 4; ++r) {
        mstate[r] = alive ? -1e30f : 0.f;
        lstate[r] = alive ? 0.f : 1.f;
    }

    if (alive) {
        {
            int r = tid >> 2, c = (tid & 3) * 16;
            const unsigned short* src = base + (size_t)(qt * 64 + r) * 3072 + hd * DH + c;
            *(uint4*)(&Qs[r * FA_DPAD + c])     = *(const uint4*)(src);
            *(uint4*)(&Qs[r * FA_DPAD + c + 8]) = *(const uint4*)(src + 8);
        }
        __syncthreads();

        bf16x8 aq[2];
        #pragma unroll
        for (int cc = 0; cc < 2; ++cc)
            aq[cc] = *(const bf16x8*)(&Qs[(wave * 16 + l16) * FA_DPAD + cc * 32 + quad * 8]);

        for (int jt = s; jt <= qt; jt += 2) {
            __syncthreads();
            {
                int r = tid >> 2, c = (tid & 3) * 16;
                const unsigned short* src = base + (size_t)(jt * 64 + r) * 3072 + 1024 + hd * DH + c;
                *(uint4*)(&Ks[r * FA_DPAD + c])     = *(const uint4*)(src);
                *(uint4*)(&Ks[r * FA_DPAD + c + 8]) = *(const uint4*)(src + 8);
            }
            {
                int j = lane, c = wave * 16;
                const unsigned short* src = base + (size_t)(jt * 64 + j) * 3072 + 2048 + hd * DH + c;
                unsigned short tmp[16];
                *(uint4*)(tmp)     = *(const uint4*)(src);
                *(uint4*)(tmp + 8) = *(const uint4*)(src + 8);
                #pragma unroll
                for (int d = 0; d < 16; ++d) Vs[(c + d) * FA_DPAD + j] = tmp[d];
            }
            __syncthreads();

            f32x4 S[4] = {};
            #pragma unroll
            for (int t = 0; t < 4; ++t)
                #pragma unroll
                for (int cc = 0; cc < 2; ++cc) {
                    bf16x8 bk = *(const bf16x8*)(&Ks[(t * 16 + l16) * FA_DPAD + cc * 32 + quad * 8]);
                    S[t] = __builtin_amdgcn_mfma_f32_16x16x32_bf16(aq[cc], bk, S[t], 0, 0, 0);
                }

            int qrow0 = qt * 64 + wave * 16 + quad * 4;
            bool diag = (jt == qt);
            float mnew[4];
            #pragma unroll
            for (int r = 0; r < 4; ++r) {
                float v = -1e30f;
                #pragma unroll
                for (int t = 0; t < 4; ++t) {
                    float sv = S[t][r] * 0.125f;
                    if (diag) {
                        int j = jt * 64 + t * 16 + l16;
                        if (j > qrow0 + r) sv = -1e30f;
                    }
                    S[t][r] = sv;
                    v = fmaxf(v, sv);
                }
                v = fmaxf(v, __shfl_xor(v, 1, 64));
                v = fmaxf(v, __shfl_xor(v, 2, 64));
                v = fmaxf(v, __shfl_xor(v, 4, 64));
                v = fmaxf(v, __shfl_xor(v, 8, 64));
                mnew[r] = fmaxf(mstate[r], v);
            }

            #pragma unroll
            for (int r = 0; r < 4; ++r) {
                float rs = 0.f;
                #pragma unroll
                for (int t = 0; t < 4; ++t) {
                    float p = __expf(S[t][r] - mnew[r]);
                    rs += p;
                    Ps[(wave * 16 + quad * 4 + r) * FA_DPAD + t * 16 + l16] = f2bf(p);
                }
                rs += __shfl_xor(rs, 1, 64);
                rs += __shfl_xor(rs, 2, 64);
                rs += __shfl_xor(rs, 4, 64);
                rs += __shfl_xor(rs, 8, 64);
                float alpha = __expf(mstate[r] - mnew[r]);
                lstate[r] = alpha * lstate[r] + rs;
                mstate[r] = mnew[r];
                #pragma unroll
                for (int t = 0; t < 4; ++t) Oacc[t][r] *= alpha;
            }

            #pragma unroll
            for (int cc = 0; cc < 2; ++cc) {
                bf16x8 ap = *(const bf16x8*)(&Ps[(wave * 16 + l16) * FA_DPAD + cc * 32 + quad * 8]);
                #pragma unroll
                for (int t = 0; t < 4; ++t) {
                    bf16x8 bv = *(const bf16x8*)(&Vs[(t * 16 + l16) * FA_DPAD + cc * 32 + quad * 8]);
                    Oacc[t] = __builtin_amdgcn_mfma_f32_16x16x32_bf16(ap, bv, Oacc[t], 0, 0, 0);
                }
            }
        }
    }

    // store unnormalized partials + (m,l)
    #pragma unroll
    for (int r = 0; r < 4; ++r) {
        int qi = qt * 64 + wave * 16 + quad * 4 + r;
        size_t row = (size_t)b * TT + qi;
        float* orow = Opart + (size_t)s * MM * D_MODEL + row * D_MODEL + hd * DH;
        #pragma unroll
        for (int t = 0; t < 4; ++t)
            orow[t * 16 + l16] = Oacc[t][r];
        if (l16 == 0) {
            float* mlp = ml + (((size_t)s * MM + row) * N_HEADS + hd) * 2;
            mlp[0] = mstate[r];
            mlp[1] = lstate[r];
        }
    }
}

// merge two j-splits -> normalized bf16 ob
__global__ void attn_merge_kernel(const float* __restrict__ Opart,
                                  const float* __restrict__ ml,
                                  unsigned short* __restrict__ ob) {
    int i = blockIdx.x * 256 + threadIdx.x;   // over MM*1024
    int row = i >> 10;
    int hd  = (i >> 6) & 15;
    const float* ml0 = ml + (((size_t)row) * N_HEADS + hd) * 2;
    const float* ml1 = ml + (((size_t)MM + row) * N_HEADS + hd) * 2;
    float m0 = ml0[0], l0 = ml0[1];
    float m1 = ml1[0], l1 = ml1[1];
    float M = fmaxf(m0, m1);
    float w0 = __expf(m0 - M), w1 = __expf(m1 - M);
    float den = w0 * l0 + w1 * l1;
    float num = w0 * Opart[i] + w1 * Opart[(size_t)MM * D_MODEL + i];
    ob[i] = f2bf(num / den);
}

// combine 2 split-K partials + bias + residual + mask; optional fused final store
__global__ void combine2_kernel(float* __restrict__ xf,
                                const float* __restrict__ pbuf,
                                const float* __restrict__ bias,
                                const float* __restrict__ mvec,
                                void* __restrict__ outp,
                                const int* __restrict__ flag, int n) {
    int i = blockIdx.x * 256 + threadIdx.x;
    if (i >= n) return;
    int row = i >> 10, col = i & 1023;
    float v = (xf[i] + pbuf[i] + pbuf[n + i] + bias[col]) * mvec[row];
    xf[i] = v;
    if (outp) {
        if (flag[0]) ((unsigned short*)outp)[i] = f2bf(v);
        else         ((float*)outp)[i] = v;
    }
}

// ---- workspace layout (bytes) ----
#define MB (1048576u)
#define WS_FLAG   0u
#define WS_MF     4096u
#define WS_EMBA   (WS_MF + 8192u)
#define WS_EMBF   (WS_EMBA + 262144u)
#define WS_BOUT   (WS_EMBF + 262144u)
#define WS_B1     (WS_BOUT + 16384u)
#define WS_B2     (WS_B1 + 65536u)
#define WS_XF     (1u*MB)    // 8 MB fp32 x
#define WS_H      (9u*MB)    // 4 MB bf16 h | ml (512 KB) after qkv GEMM | W2 partials (FFN)
#define WS_QKV    (13u*MB)   // 12 MB bf16
#define WS_OB     (25u*MB)   // 4 MB bf16
#define WS_PART   (9u*MB)    // 16 MB fp32 W2 split-K partials (FFN phase, h/qkv dead)
#define WS_ML     (9u*MB)    // 512 KB fp32 attn (m,l)   (attention phase, h dead)
#define WS_FF1    (29u*MB)   // 16 MB bf16 ff1 (FFN) | attn O-partials (attention phase)
#define WS_OPART  (29u*MB)
#define WS_WQKV   (45u*MB)   // 6 MB (3072 x 1024)
#define WS_WOUT   (51u*MB)   // 2 MB
#define WS_W1     (53u*MB)   // 8 MB (4096 x 1024)
#define WS_W2     (61u*MB)   // 8 MB (1024 x 4096)  end: 69 MB

extern "C" void kernel_launch(void* const* d_in, const int* in_sizes, int n_in,
                              void* d_out, int out_size, void* d_ws, size_t ws_size,
                              hipStream_t stream) {
    const void* x_in  = d_in[0];
    const void* m_in  = d_in[1];
    const int*  l_in  = (const int*)d_in[2];
    const void* Wqkv  = d_in[3];
    const void* Wout  = d_in[4];
    const void* boutp = d_in[5];
    const void* ada_a = d_in[6];
    const void* ada_f = d_in[7];
    const void* W1    = d_in[8];
    const void* b1    = d_in[9];
    const void* W2    = d_in[10];
    const void* b2    = d_in[11];

    char* ws = (char*)d_ws;
    int*            flag = (int*)(ws + WS_FLAG);
    float*          mf   = (float*)(ws + WS_MF);
    float*          embA = (float*)(ws + WS_EMBA);
    float*          embF = (float*)(ws + WS_EMBF);
    float*          boutf= (float*)(ws + WS_BOUT);
    float*          b1f  = (float*)(ws + WS_B1);
    float*          b2f  = (float*)(ws + WS_B2);
    float*          xf   = (float*)(ws + WS_XF);
    unsigned short* h    = (unsigned short*)(ws + WS_H);
    unsigned short* qkv  = (unsigned short*)(ws + WS_QKV);
    unsigned short* ob   = (unsigned short*)(ws + WS_OB);
    float*          part = (float*)(ws + WS_PART);
    float*          mlb  = (float*)(ws + WS_ML);
    float*          opart= (float*)(ws + WS_OPART);
    unsigned short* ff1  = (unsigned short*)(ws + WS_FF1);
    unsigned short* wqkvt= (unsigned short*)(ws + WS_WQKV);
    unsigned short* woutt= (unsigned short*)(ws + WS_WOUT);
    unsigned short* w1t  = (unsigned short*)(ws + WS_W1);
    unsigned short* w2t  = (unsigned short*)(ws + WS_W2);

    const int n = MM * D_MODEL;

    detect_kernel<<<1, 256, 0, stream>>>((const unsigned short*)x_in, flag);
    load_f32_kernel<<<n / 256, 256, 0, stream>>>(x_in, xf, flag, n);
    load_small_kernel<<<(157696 + 255) / 256, 256, 0, stream>>>(
        m_in, ada_a, ada_f, boutp, b1, b2, mf, embA, embF, boutf, b1f, b2f, flag);

    const long long nqkv = (long long)D_MODEL * 3 * D_MODEL;
    const long long nsq  = (long long)D_MODEL * D_MODEL;
    const long long nw1  = (long long)D_MODEL * 4 * D_MODEL;

    for (int i = 0; i < N_LAYERS; ++i) {
        transpose_layer_kernel<<<12288, 256, 0, stream>>>(
            Wqkv, Wout, W1, W2, wqkvt, woutt, w1t, w2t, flag,
            i * nqkv, i * nsq, i * nw1, i * nw1);

        // ---- attention sub-block ----
        adaln_kernel<<<MM, 256, 0, stream>>>(xf, embA + (size_t)i * N_LEVELS * 2 * D_MODEL, l_in, mf, h);
        gemm8_kernel<4,2,2,2><<<dim3(3072 / 64, MM / 128), 256, 0, stream>>>(
            h, 1024, wqkvt, 1024, nullptr, qkv, nullptr, nullptr, mf, nullptr,
            MM, 3072, 1024, EPI_STORE);
        fattn_split_kernel<<<dim3(TT / 64, N_HEADS, BB * 2), 256, 0, stream>>>(qkv, mf, opart, mlb);
        attn_merge_kernel<<<n / 256, 256, 0, stream>>>(opart, mlb, ob);
        gemm8_kernel<2,2,4,2><<<dim3(1024 / 64, MM / 128), 512, 0, stream>>>(
            ob, 1024, woutt, 1024, boutf + (size_t)i * D_MODEL, nullptr, xf, xf, mf, nullptr,
            MM, 1024, 1024, EPI_RESID);
        // ---- FFN sub-block ----
        adaln_kernel<<<MM, 256, 0, stream>>>(xf, embF + (size_t)i * N_LEVELS * 2 * D_MODEL, l_in, mf, h);
        gemm8_kernel<4,2,2,4><<<dim3(4096 / 128, MM / 128), 512, 0, stream>>>(
            h, 1024, w1t, 1024, b1f + (size_t)i * 4 * D_MODEL, ff1, nullptr, nullptr, mf, nullptr,
            MM, 4096, 1024, EPI_GELU);
        gemm8_kernel<2,2,4,2><<<dim3(1024 / 64, MM / 128, 2), 512, 0, stream>>>(
            ff1, 4096, w2t, 4096, nullptr, nullptr, nullptr, nullptr, mf, part,
            MM, 1024, 2048, EPI_PART);
        combine2_kernel<<<n / 256, 256, 0, stream>>>(
            xf, part, b2f + (size_t)i * D_MODEL, mf,
            (i == N_LAYERS - 1) ? d_out : nullptr, flag, n);
    }
}

// Round 3
// 938.804 us; speedup vs baseline: 1.0646x; 1.0355x over previous
//
#include <hip/hip_runtime.h>

#define D_MODEL 1024
#define N_HEADS 16
#define DH 64
#define N_LAYERS 4
#define N_LEVELS 8
#define BB 2
#define TT 1024
#define MM (BB*TT)
#define EPSV 1e-5f

typedef float f32x4 __attribute__((ext_vector_type(4)));
typedef short bf16x8 __attribute__((ext_vector_type(8)));
typedef unsigned short u16x4 __attribute__((ext_vector_type(4)));

__device__ __forceinline__ float bf2f(unsigned short u) {
    union { unsigned int i; float f; } c; c.i = ((unsigned int)u) << 16; return c.f;
}
__device__ __forceinline__ unsigned short f2bf(float f) {
    union { float f; unsigned int i; } c; c.f = f;
    unsigned int x = c.i;
    return (unsigned short)((x + 0x7fffu + ((x >> 16) & 1u)) >> 16);  // RNE
}
__device__ __forceinline__ float cvt_in(const void* src, long long j, int isbf) {
    return isbf ? bf2f(((const unsigned short*)src)[j]) : ((const float*)src)[j];
}

// async global->LDS, 16 B per lane; LDS dest = wave-uniform base + lane*16
__device__ __forceinline__ void gl_lds16(const unsigned short* g, unsigned short* l) {
    __builtin_amdgcn_global_load_lds(
        (const __attribute__((address_space(1))) unsigned int*)g,
        (__attribute__((address_space(3))) unsigned int*)l,
        16, 0, 0);
}

// counted vmcnt wait (T4): never drain to 0 in the main loop
template<int N> __device__ __forceinline__ void wait_vm() {
    asm volatile("s_waitcnt vmcnt(%0)" :: "i"(N) : "memory");
}

// ---- dtype detection (fp32 vs bf16 input buffers) ----
__global__ void detect_kernel(const unsigned short* __restrict__ x, int* __restrict__ flag) {
    __shared__ int cnts[256];
    int cnt = 0;
    for (int i = threadIdx.x; i < 16384; i += 256) {
        unsigned short u = x[2 * i];
        int e = (u >> 7) & 0xFF;
        if (e >= 110 && e <= 140) cnt++;
    }
    cnts[threadIdx.x] = cnt;
    __syncthreads();
    for (int s = 128; s; s >>= 1) {
        if (threadIdx.x < s) cnts[threadIdx.x] += cnts[threadIdx.x + s];
        __syncthreads();
    }
    if (threadIdx.x == 0) flag[0] = (cnts[0] > 12000) ? 1 : 0;
}

// ---- converters ----
__global__ void load_f32_kernel(const void* __restrict__ src, float* __restrict__ dst,
                                const int* __restrict__ flag, int n) {
    int i = blockIdx.x * 256 + threadIdx.x;
    if (i >= n) return;
    dst[i] = cvt_in(src, i, flag[0]);
}
__global__ void load_small_kernel(const void* m_in, const void* aa, const void* af_,
                                  const void* bo, const void* b1, const void* b2,
                                  float* mf, float* embA, float* embF,
                                  float* boutf, float* b1f, float* b2f,
                                  const int* __restrict__ flag) {
    int i = blockIdx.x * 256 + threadIdx.x;
    int isbf = flag[0];
    if (i < 2048)        mf[i] = cvt_in(m_in, i, isbf);
    else if (i < 67584)  embA[i - 2048] = cvt_in(aa, i - 2048, isbf);
    else if (i < 133120) embF[i - 67584] = cvt_in(af_, i - 67584, isbf);
    else if (i < 137216) boutf[i - 133120] = cvt_in(bo, i - 133120, isbf);
    else if (i < 153600) b1f[i - 137216] = cvt_in(b1, i - 137216, isbf);
    else if (i < 157696) b2f[i - 153600] = cvt_in(b2, i - 153600, isbf);
}

// ---- per-layer fused weight transpose: dst(N,K) bf16 <- src(K,N) ----
__global__ __launch_bounds__(256)
void transpose_layer_kernel(const void* Wqkv, const void* Wo, const void* W1, const void* W2,
                            unsigned short* wq, unsigned short* wo,
                            unsigned short* w1, unsigned short* w2,
                            const int* __restrict__ flag,
                            long long o_qkv, long long o_o, long long o_1, long long o_2) {
    __shared__ float tile[32][33];
    int bid = blockIdx.x;
    const void* src; unsigned short* dst; long long off; int N, K, nt, kt;
    if (bid < 3072)      { int t = bid;        src = Wqkv; dst = wq; off = o_qkv; N = 3072; K = 1024; nt = t % 96;  kt = t / 96; }
    else if (bid < 4096) { int t = bid - 3072; src = Wo;   dst = wo; off = o_o;   N = 1024; K = 1024; nt = t % 32;  kt = t / 32; }
    else if (bid < 8192) { int t = bid - 4096; src = W1;   dst = w1; off = o_1;   N = 4096; K = 1024; nt = t % 128; kt = t / 128; }
    else                 { int t = bid - 8192; src = W2;   dst = w2; off = o_2;   N = 1024; K = 4096; nt = t % 32;  kt = t / 32; }
    int n0 = nt * 32, k0 = kt * 32;
    int r = threadIdx.x >> 5, c = threadIdx.x & 31;
    int isbf = flag[0];
    #pragma unroll
    for (int rr = 0; rr < 4; ++rr) {
        int k = k0 + r + rr * 8;
        tile[r + rr * 8][c] = cvt_in(src, off + (long long)k * N + n0 + c, isbf);
    }
    __syncthreads();
    #pragma unroll
    for (int rr = 0; rr < 4; ++rr) {
        int n = n0 + r + rr * 8;
        dst[(size_t)n * K + k0 + c] = f2bf(tile[c][r + rr * 8]);
    }
}

// ---- dual block reduction (blockDim.x == 256) ----
__device__ __forceinline__ void blk_sum2_256(float& a, float& b, float* red) {
    #pragma unroll
    for (int off = 32; off; off >>= 1) {
        a += __shfl_down(a, off, 64);
        b += __shfl_down(b, off, 64);
    }
    int tid = threadIdx.x;
    __syncthreads();
    if ((tid & 63) == 0) { red[tid >> 6] = a; red[4 + (tid >> 6)] = b; }
    __syncthreads();
    a = red[0] + red[1] + red[2] + red[3];
    b = red[4] + red[5] + red[6] + red[7];
}

// ---- AdaLN (single pass mean/var; float4 loads; masked rows write zeros) ----
__global__ __launch_bounds__(256)
void adaln_kernel(const float* __restrict__ x,
                  const float* __restrict__ emb,
                  const int* __restrict__ lvl,
                  const float* __restrict__ mvec,
                  unsigned short* __restrict__ h) {
    __shared__ float red[8];
    int row = blockIdx.x;
    int b = row / TT;
    int tid = threadIdx.x;
    const float* xr = x + (size_t)row * D_MODEL;
    float mval = mvec[row];
    unsigned short* hr = h + (size_t)row * D_MODEL;

    if (mval == 0.0f) {   // block-uniform: whole block is one row
        u16x4 z = (u16x4)0;
        *(u16x4*)(hr + 4 * tid) = z;
        return;
    }

    f32x4 xv = *(const f32x4*)(xr + 4 * tid);
    float s = xv[0] + xv[1] + xv[2] + xv[3];
    float ss = xv[0]*xv[0] + xv[1]*xv[1] + xv[2]*xv[2] + xv[3]*xv[3];
    blk_sum2_256(s, ss, red);
    float mu = s * (1.0f / D_MODEL);
    float var = ss * (1.0f / D_MODEL) - mu * mu;
    float rstd = rsqrtf(var + EPSV);

    int lv = lvl[b];
    const float* g = emb + (size_t)lv * (2 * D_MODEL);
    f32x4 lg = *(const f32x4*)(g + 4 * tid);
    f32x4 lb = *(const f32x4*)(g + D_MODEL + 4 * tid);
    u16x4 r;
    #pragma unroll
    for (int c = 0; c < 4; ++c) {
        float hn = (xv[c] - mu) * rstd;
        float h2 = 2.0f * (1.0f - 0.1f * hn) * hn;
        float o = __expf(lg[c]) * h2 + lb[c];
        r[c] = f2bf(o * mval);
    }
    *(u16x4*)(hr + 4 * tid) = r;
}

// ---- MFMA GEMM: depth-2 pipeline, 4 LDS buffers, counted vmcnt (T3+T4) ----
#define EPI_STORE 0
#define EPI_GELU  1
#define EPI_RESID 2
#define EPI_PART  3

template<int MI, int NI, int WR, int WC>
__global__ __launch_bounds__(WR * WC * 64)
void gemm8_kernel(const unsigned short* __restrict__ A, int lda,
                  const unsigned short* __restrict__ BT, int ldb,
                  const float* __restrict__ bias,
                  unsigned short* __restrict__ outb,
                  const float* __restrict__ xin,
                  float* __restrict__ xout,
                  const float* __restrict__ mvec,
                  float* __restrict__ pbuf,
                  int M, int N, int K, int mode) {
    constexpr int BM = WR * MI * 16;
    constexpr int BN = WC * NI * 16;
    constexpr int NW = WR * WC;
    constexpr int NSA = BM / 16;          // A stage chunks (16 rows x 32 k each)
    constexpr int NSB = BN / 16;
    static_assert(NSA % NW == 0, "A staging must divide evenly over waves");
    constexpr int LA  = NSA / NW;         // A loads per wave per K-step
    constexpr int LB0 = NSB / NW;         // B loads: waves < LBr issue one extra
    constexpr int LBr = NSB % NW;
    __shared__ __align__(16) unsigned short As[4][BM * 32];
    __shared__ __align__(16) unsigned short Bs[4][BN * 32];
    __shared__ int alive;
    int tid = threadIdx.x;
    int wave = tid >> 6;
    int lane = tid & 63;
    int quad = lane >> 4;
    int l16  = lane & 15;
    int tileM = blockIdx.y * BM;
    int tileN = blockIdx.x * BN;
    int wm = (wave % WR) * MI * 16;
    int wn = (wave / WR) * NI * 16;

    // mask-skip: if every row of this M-tile is masked, skip the K-loop;
    // epilogue then writes exact zeros (STORE/PART) or (xin+bias)*0 (RESID).
    if (tid == 0) alive = 0;
    __syncthreads();
    if (tid < BM && mvec[tileM + tid] != 0.0f) alive = 1;
    __syncthreads();

    f32x4 acc[MI][NI] = {};

    if (alive) {
        long long zoff = (long long)blockIdx.z * K;
        const unsigned short* Ab = A  + zoff + (size_t)(tileM + (lane >> 2)) * lda + (lane & 3) * 8;
        const unsigned short* Bb = BT + zoff + (size_t)(tileN + (lane >> 2)) * ldb + (lane & 3) * 8;

        auto stage = [&](int t, int buf) {
            int k0 = t * 32;
            #pragma unroll
            for (int st = wave, i = 0; i < LA; st += NW, ++i)
                gl_lds16(Ab + (size_t)st * 16 * lda + k0, &As[buf][st * 512]);
            for (int st = wave; st < NSB; st += NW)
                gl_lds16(Bb + (size_t)st * 16 * ldb + k0, &Bs[buf][st * 512]);
        };
        auto compute = [&](int buf) {
            __builtin_amdgcn_sched_barrier(0);   // keep ds_reads behind the barrier
            bf16x8 af[MI], bf[NI];
            #pragma unroll
            for (int mi = 0; mi < MI; ++mi)
                af[mi] = *(const bf16x8*)(&As[buf][(wm + mi * 16 + l16) * 32 + quad * 8]);
            #pragma unroll
            for (int ni = 0; ni < NI; ++ni)
                bf[ni] = *(const bf16x8*)(&Bs[buf][(wn + ni * 16 + l16) * 32 + quad * 8]);
            #pragma unroll
            for (int mi = 0; mi < MI; ++mi)
                #pragma unroll
                for (int ni = 0; ni < NI; ++ni)
                    acc[mi][ni] = __builtin_amdgcn_mfma_f32_16x16x32_bf16(af[mi], bf[ni], acc[mi][ni], 0, 0, 0);
        };

        int nt = K / 32;                  // >= 16 for all our shapes
        stage(0, 0);
        stage(1, 1);
        // steady state: tiles t+1, t+2 in flight across the barrier (2L outstanding)
        for (int t = 0; t + 2 < nt; ++t) {
            stage(t + 2, (t + 2) & 3);
            if (LBr && wave < LBr) wait_vm<2 * (LA + LB0 + 1)>();
            else                   wait_vm<2 * (LA + LB0)>();
            __builtin_amdgcn_s_barrier();
            compute(t & 3);
        }
        {   // t = nt-2: only tile nt-1 in flight
            if (LBr && wave < LBr) wait_vm<LA + LB0 + 1>();
            else                   wait_vm<LA + LB0>();
            __builtin_amdgcn_s_barrier();
            compute((nt - 2) & 3);
        }
        {   // t = nt-1: drain
            wait_vm<0>();
            __builtin_amdgcn_s_barrier();
            compute((nt - 1) & 3);
        }
    }

    #pragma unroll
    for (int mi = 0; mi < MI; ++mi)
    #pragma unroll
    for (int ni = 0; ni < NI; ++ni) {
        #pragma unroll
        for (int r = 0; r < 4; ++r) {
            int row = tileM + wm + mi * 16 + quad * 4 + r;
            int col = tileN + wn + ni * 16 + l16;
            float v = acc[mi][ni][r];
            size_t idx = (size_t)row * N + col;
            if (mode == EPI_STORE) {
                outb[idx] = f2bf(v);
            } else if (mode == EPI_GELU) {
                v += bias[col];
                float gel = 0.5f * v * (1.0f + erff(v * 0.70710678118654752f));
                outb[idx] = f2bf(gel);
            } else if (mode == EPI_RESID) {
                v += bias[col];
                xout[idx] = (xin[idx] + v) * mvec[row];
            } else {
                pbuf[(size_t)blockIdx.z * M * N + idx] = v;
            }
        }
    }
}

// ---- split-j flash attention: 2 blocks per (qt,hd,b), j-tiles by parity ----
#define FA_DPAD 72

__global__ __launch_bounds__(256)
void fattn_split_kernel(const unsigned short* __restrict__ qkv,
                        const float* __restrict__ mvec,
                        float* __restrict__ Opart,   // [2][MM][1024] fp32 unnormalized
                        float* __restrict__ ml) {    // [2][MM][16][2] fp32 (m,l)
    __shared__ __align__(16) unsigned short Qs[64 * FA_DPAD];
    __shared__ __align__(16) unsigned short Ks[64 * FA_DPAD];
    __shared__ __align__(16) unsigned short Vs[64 * FA_DPAD];
    __shared__ __align__(16) unsigned short Ps[64 * FA_DPAD];
    __shared__ int alive_s;

    int qt  = blockIdx.x;            // 0..15
    int hd  = blockIdx.y;
    int b   = blockIdx.z >> 1;
    int s   = blockIdx.z & 1;        // j-parity split
    int tid = threadIdx.x;
    int wave = tid >> 6;
    int lane = tid & 63;
    int quad = lane >> 4;
    int l16  = lane & 15;

    // mask-skip: whole q-tile masked -> write zero partials with (m=0, l=1)
    if (tid == 0) alive_s = 0;
    __syncthreads();
    if (tid < 64 && mvec[(size_t)b * TT + qt * 64 + tid] != 0.0f) alive_s = 1;
    __syncthreads();
    bool alive = alive_s != 0;

    const unsigned short* base = qkv + (size_t)b * TT * 3072;

    f32x4 Oacc[4] = {};
    float mstate[4], lstate[4];
    #pragma unroll
    for (int r = 0; r < 4; ++r) {
        mstate[r] = alive ? -1e30f : 0.f;
        lstate[r] = alive ? 0.f : 1.f;
    }

    if (alive) {
        {
            int r = tid >> 2, c = (tid & 3) * 16;
            const unsigned short* src = base + (size_t)(qt * 64 + r) * 3072 + hd * DH + c;
            *(uint4*)(&Qs[r * FA_DPAD + c])     = *(const uint4*)(src);
            *(uint4*)(&Qs[r * FA_DPAD + c + 8]) = *(const uint4*)(src + 8);
        }
        __syncthreads();

        bf16x8 aq[2];
        #pragma unroll
        for (int cc = 0; cc < 2; ++cc)
            aq[cc] = *(const bf16x8*)(&Qs[(wave * 16 + l16) * FA_DPAD + cc * 32 + quad * 8]);

        for (int jt = s; jt <= qt; jt += 2) {
            __syncthreads();
            {
                int r = tid >> 2, c = (tid & 3) * 16;
                const unsigned short* src = base + (size_t)(jt * 64 + r) * 3072 + 1024 + hd * DH + c;
                *(uint4*)(&Ks[r * FA_DPAD + c])     = *(const uint4*)(src);
                *(uint4*)(&Ks[r * FA_DPAD + c + 8]) = *(const uint4*)(src + 8);
            }
            {
                int j = lane, c = wave * 16;
                const unsigned short* src = base + (size_t)(jt * 64 + j) * 3072 + 2048 + hd * DH + c;
                unsigned short tmp[16];
                *(uint4*)(tmp)     = *(const uint4*)(src);
                *(uint4*)(tmp + 8) = *(const uint4*)(src + 8);
                #pragma unroll
                for (int d = 0; d < 16; ++d) Vs[(c + d) * FA_DPAD + j] = tmp[d];
            }
            __syncthreads();

            f32x4 S[4] = {};
            #pragma unroll
            for (int t = 0; t < 4; ++t)
                #pragma unroll
                for (int cc = 0; cc < 2; ++cc) {
                    bf16x8 bk = *(const bf16x8*)(&Ks[(t * 16 + l16) * FA_DPAD + cc * 32 + quad * 8]);
                    S[t] = __builtin_amdgcn_mfma_f32_16x16x32_bf16(aq[cc], bk, S[t], 0, 0, 0);
                }

            int qrow0 = qt * 64 + wave * 16 + quad * 4;
            bool diag = (jt == qt);
            float mnew[4];
            #pragma unroll
            for (int r = 0; r < 4; ++r) {
                float v = -1e30f;
                #pragma unroll
                for (int t = 0; t < 4; ++t) {
                    float sv = S[t][r] * 0.125f;
                    if (diag) {
                        int j = jt * 64 + t * 16 + l16;
                        if (j > qrow0 + r) sv = -1e30f;
                    }
                    S[t][r] = sv;
                    v = fmaxf(v, sv);
                }
                v = fmaxf(v, __shfl_xor(v, 1, 64));
                v = fmaxf(v, __shfl_xor(v, 2, 64));
                v = fmaxf(v, __shfl_xor(v, 4, 64));
                v = fmaxf(v, __shfl_xor(v, 8, 64));
                mnew[r] = fmaxf(mstate[r], v);
            }

            #pragma unroll
            for (int r = 0; r < 4; ++r) {
                float rs = 0.f;
                #pragma unroll
                for (int t = 0; t < 4; ++t) {
                    float p = __expf(S[t][r] - mnew[r]);
                    rs += p;
                    Ps[(wave * 16 + quad * 4 + r) * FA_DPAD + t * 16 + l16] = f2bf(p);
                }
                rs += __shfl_xor(rs, 1, 64);
                rs += __shfl_xor(rs, 2, 64);
                rs += __shfl_xor(rs, 4, 64);
                rs += __shfl_xor(rs, 8, 64);
                float alpha = __expf(mstate[r] - mnew[r]);
                lstate[r] = alpha * lstate[r] + rs;
                mstate[r] = mnew[r];
                #pragma unroll
                for (int t = 0; t < 4; ++t) Oacc[t][r] *= alpha;
            }

            #pragma unroll
            for (int cc = 0; cc < 2; ++cc) {
                bf16x8 ap = *(const bf16x8*)(&Ps[(wave * 16 + l16) * FA_DPAD + cc * 32 + quad * 8]);
                #pragma unroll
                for (int t = 0; t < 4; ++t) {
                    bf16x8 bv = *(const bf16x8*)(&Vs[(t * 16 + l16) * FA_DPAD + cc * 32 + quad * 8]);
                    Oacc[t] = __builtin_amdgcn_mfma_f32_16x16x32_bf16(ap, bv, Oacc[t], 0, 0, 0);
                }
            }
        }
    }

    // store unnormalized partials + (m,l)
    #pragma unroll
    for (int r = 0; r < 4; ++r) {
        int qi = qt * 64 + wave * 16 + quad * 4 + r;
        size_t row = (size_t)b * TT + qi;
        float* orow = Opart + (size_t)s * MM * D_MODEL + row * D_MODEL + hd * DH;
        #pragma unroll
        for (int t = 0; t < 4; ++t)
            orow[t * 16 + l16] = Oacc[t][r];
        if (l16 == 0) {
            float* mlp = ml + (((size_t)s * MM + row) * N_HEADS + hd) * 2;
            mlp[0] = mstate[r];
            mlp[1] = lstate[r];
        }
    }
}

// merge two j-splits -> normalized bf16 ob
__global__ void attn_merge_kernel(const float* __restrict__ Opart,
                                  const float* __restrict__ ml,
                                  unsigned short* __restrict__ ob) {
    int i = blockIdx.x * 256 + threadIdx.x;   // over MM*1024
    int row = i >> 10;
    int hd  = (i >> 6) & 15;
    const float* ml0 = ml + (((size_t)row) * N_HEADS + hd) * 2;
    const float* ml1 = ml + (((size_t)MM + row) * N_HEADS + hd) * 2;
    float m0 = ml0[0], l0 = ml0[1];
    float m1 = ml1[0], l1 = ml1[1];
    float M = fmaxf(m0, m1);
    float w0 = __expf(m0 - M), w1 = __expf(m1 - M);
    float den = w0 * l0 + w1 * l1;
    float num = w0 * Opart[i] + w1 * Opart[(size_t)MM * D_MODEL + i];
    ob[i] = f2bf(num / den);
}

// combine 2 split-K partials + bias + residual + mask; optional fused final store
__global__ void combine2_kernel(float* __restrict__ xf,
                                const float* __restrict__ pbuf,
                                const float* __restrict__ bias,
                                const float* __restrict__ mvec,
                                void* __restrict__ outp,
                                const int* __restrict__ flag, int n) {
    int i = blockIdx.x * 256 + threadIdx.x;
    if (i >= n) return;
    int row = i >> 10, col = i & 1023;
    float v = (xf[i] + pbuf[i] + pbuf[n + i] + bias[col]) * mvec[row];
    xf[i] = v;
    if (outp) {
        if (flag[0]) ((unsigned short*)outp)[i] = f2bf(v);
        else         ((float*)outp)[i] = v;
    }
}

// ---- workspace layout (bytes) ----
#define MB (1048576u)
#define WS_FLAG   0u
#define WS_MF     4096u
#define WS_EMBA   (WS_MF + 8192u)
#define WS_EMBF   (WS_EMBA + 262144u)
#define WS_BOUT   (WS_EMBF + 262144u)
#define WS_B1     (WS_BOUT + 16384u)
#define WS_B2     (WS_B1 + 65536u)
#define WS_XF     (1u*MB)    // 8 MB fp32 x
#define WS_H      (9u*MB)    // 4 MB bf16 h | ml (512 KB) after qkv GEMM | W2 partials (FFN)
#define WS_QKV    (13u*MB)   // 12 MB bf16
#define WS_OB     (25u*MB)   // 4 MB bf16
#define WS_PART   (9u*MB)    // 16 MB fp32 W2 split-K partials (FFN phase, h/qkv dead)
#define WS_ML     (9u*MB)    // 512 KB fp32 attn (m,l)   (attention phase, h dead)
#define WS_FF1    (29u*MB)   // 16 MB bf16 ff1 (FFN) | attn O-partials (attention phase)
#define WS_OPART  (29u*MB)
#define WS_WQKV   (45u*MB)   // 6 MB (3072 x 1024)
#define WS_WOUT   (51u*MB)   // 2 MB
#define WS_W1     (53u*MB)   // 8 MB (4096 x 1024)
#define WS_W2     (61u*MB)   // 8 MB (1024 x 4096)  end: 69 MB

extern "C" void kernel_launch(void* const* d_in, const int* in_sizes, int n_in,
                              void* d_out, int out_size, void* d_ws, size_t ws_size,
                              hipStream_t stream) {
    const void* x_in  = d_in[0];
    const void* m_in  = d_in[1];
    const int*  l_in  = (const int*)d_in[2];
    const void* Wqkv  = d_in[3];
    const void* Wout  = d_in[4];
    const void* boutp = d_in[5];
    const void* ada_a = d_in[6];
    const void* ada_f = d_in[7];
    const void* W1    = d_in[8];
    const void* b1    = d_in[9];
    const void* W2    = d_in[10];
    const void* b2    = d_in[11];

    char* ws = (char*)d_ws;
    int*            flag = (int*)(ws + WS_FLAG);
    float*          mf   = (float*)(ws + WS_MF);
    float*          embA = (float*)(ws + WS_EMBA);
    float*          embF = (float*)(ws + WS_EMBF);
    float*          boutf= (float*)(ws + WS_BOUT);
    float*          b1f  = (float*)(ws + WS_B1);
    float*          b2f  = (float*)(ws + WS_B2);
    float*          xf   = (float*)(ws + WS_XF);
    unsigned short* h    = (unsigned short*)(ws + WS_H);
    unsigned short* qkv  = (unsigned short*)(ws + WS_QKV);
    unsigned short* ob   = (unsigned short*)(ws + WS_OB);
    float*          part = (float*)(ws + WS_PART);
    float*          mlb  = (float*)(ws + WS_ML);
    float*          opart= (float*)(ws + WS_OPART);
    unsigned short* ff1  = (unsigned short*)(ws + WS_FF1);
    unsigned short* wqkvt= (unsigned short*)(ws + WS_WQKV);
    unsigned short* woutt= (unsigned short*)(ws + WS_WOUT);
    unsigned short* w1t  = (unsigned short*)(ws + WS_W1);
    unsigned short* w2t  = (unsigned short*)(ws + WS_W2);

    const int n = MM * D_MODEL;

    detect_kernel<<<1, 256, 0, stream>>>((const unsigned short*)x_in, flag);
    load_f32_kernel<<<n / 256, 256, 0, stream>>>(x_in, xf, flag, n);
    load_small_kernel<<<(157696 + 255) / 256, 256, 0, stream>>>(
        m_in, ada_a, ada_f, boutp, b1, b2, mf, embA, embF, boutf, b1f, b2f, flag);

    const long long nqkv = (long long)D_MODEL * 3 * D_MODEL;
    const long long nsq  = (long long)D_MODEL * D_MODEL;
    const long long nw1  = (long long)D_MODEL * 4 * D_MODEL;

    for (int i = 0; i < N_LAYERS; ++i) {
        transpose_layer_kernel<<<12288, 256, 0, stream>>>(
            Wqkv, Wout, W1, W2, wqkvt, woutt, w1t, w2t, flag,
            i * nqkv, i * nsq, i * nw1, i * nw1);

        // ---- attention sub-block ----
        adaln_kernel<<<MM, 256, 0, stream>>>(xf, embA + (size_t)i * N_LEVELS * 2 * D_MODEL, l_in, mf, h);
        gemm8_kernel<4,2,2,2><<<dim3(3072 / 64, MM / 128), 256, 0, stream>>>(
            h, 1024, wqkvt, 1024, nullptr, qkv, nullptr, nullptr, mf, nullptr,
            MM, 3072, 1024, EPI_STORE);
        fattn_split_kernel<<<dim3(TT / 64, N_HEADS, BB * 2), 256, 0, stream>>>(qkv, mf, opart, mlb);
        attn_merge_kernel<<<n / 256, 256, 0, stream>>>(opart, mlb, ob);
        gemm8_kernel<2,2,4,2><<<dim3(1024 / 64, MM / 128), 512, 0, stream>>>(
            ob, 1024, woutt, 1024, boutf + (size_t)i * D_MODEL, nullptr, xf, xf, mf, nullptr,
            MM, 1024, 1024, EPI_RESID);
        // ---- FFN sub-block ----
        adaln_kernel<<<MM, 256, 0, stream>>>(xf, embF + (size_t)i * N_LEVELS * 2 * D_MODEL, l_in, mf, h);
        gemm8_kernel<4,2,2,4><<<dim3(4096 / 128, MM / 128), 512, 0, stream>>>(
            h, 1024, w1t, 1024, b1f + (size_t)i * 4 * D_MODEL, ff1, nullptr, nullptr, mf, nullptr,
            MM, 4096, 1024, EPI_GELU);
        gemm8_kernel<2,2,4,2><<<dim3(1024 / 64, MM / 128, 2), 512, 0, stream>>>(
            ff1, 4096, w2t, 4096, nullptr, nullptr, nullptr, nullptr, mf, part,
            MM, 1024, 2048, EPI_PART);
        combine2_kernel<<<n / 256, 256, 0, stream>>>(
            xf, part, b2f + (size_t)i * D_MODEL, mf,
            (i == N_LAYERS - 1) ? d_out : nullptr, flag, n);
    }
}